// Round 7
// baseline (187.882 us; speedup 1.0000x reference)
//
#include <hip/hip_runtime.h>
#include <math.h>

#define BATCH 32
#define HH 512
#define WW 512
#define NC 32        // cells per side
#define NORI 6
#define TP 66        // 64 + 2 halo
#define PITCH 67     // odd pitch -> conflict-light LDS
#define QCAP 64      // ambiguity queue capacity (expected ~0.16/block)

// ---- round-5-verbatim numpy downstream (slow path only, emitted ONCE) ----
__device__ __forceinline__ int bin_of(float a) {
    const float deg = __fmul_rn(a, 57.29577951308232f);
    float m = fmodf(deg, 180.0f);
    if (m < 0.0f) m = __fadd_rn(m, 180.0f);
    const int b = (int)floorf(__fdiv_rn(m, 30.0f));
    return min(max(b, 0), NORI - 1);
}
__device__ __forceinline__ float ulp_step(float x, int k) {
    const int i = __float_as_int(x);
    int key = (i >= 0) ? i : -(i & 0x7FFFFFFF);
    key += k;
    const int r = (key >= 0) ? key : (int)(0x80000000u | (unsigned)(-key));
    return __int_as_float(r);
}
__device__ __forceinline__ void deposit(float acc[NORI], int bin, float val) {
#pragma unroll
    for (int o = 0; o < NORI; ++o) acc[o] += (bin == o) ? val : 0.0f;
}

// One block = 64x64 pixels = 4x4 cells. Branch-lean fast loop (5-halfplane
// sign-count classifier); pixels within 1e-5 rad of a bin boundary are queued
// and handled post-loop by the round-5 atan2f +-2ulp policy (one code copy).
__global__ __launch_bounds__(256, 8) void hog_cells_kernel(const float* __restrict__ x,
                                                           float* __restrict__ cells) {
    const int b = blockIdx.z;
    const int tid = threadIdx.x;
    const int R0 = 64 * blockIdx.y - 1;   // tile origin incl. halo
    const int C0 = 64 * blockIdx.x - 1;

    __shared__ float gray[TP * PITCH];
    __shared__ float hist[16][NORI];      // per-cell correction hist (amb only)
    __shared__ float qgy[QCAP], qgx[QCAP], qmag[QCAP];
    __shared__ int   qcell[QCAP];
    __shared__ int   qcount;

    if (tid < 16 * NORI) ((float*)hist)[tid] = 0.0f;
    if (tid == 0) qcount = 0;

    const float* img = x + (size_t)b * 3 * HH * WW;
    for (int i = tid; i < TP * TP; i += 256) {
        const int lr = i / TP, lc = i - lr * TP;
        const int r = R0 + lr, c = C0 + lc;
        float g = 0.0f;
        if ((unsigned)r < (unsigned)HH && (unsigned)c < (unsigned)WW) {
            const size_t idx = (size_t)r * WW + c;
            // (0.299*R + 0.587*G) + 0.114*B, all f32, no FMA contraction
            g = __fadd_rn(__fadd_rn(__fmul_rn(0.299f, img[idx]),
                                    __fmul_rn(0.587f, img[idx + (size_t)HH * WW])),
                          __fmul_rn(0.114f, img[idx + (size_t)2 * HH * WW]));
        }
        gray[lr * PITCH + lc] = g;
    }
    __syncthreads();

    const int wave = tid >> 6, lane = tid & 63;
    const int rl = wave * 16 + (lane & 15);        // local pixel row 0..63
    const int clb = (lane >> 4) * 16;              // local pixel col base
    const int rg = R0 + 1 + rl;                    // global pixel row
    const bool row_ok = (rg >= 1) && (rg < HH - 1);
    const int mycell = wave * 4 + (lane >> 4);     // cell index in 4x4 grid

    const float CC = 0.86602540378443864676f, SS = 0.5f, EPS = 1e-5f;
    float acc[NORI] = {0, 0, 0, 0, 0, 0};

#pragma unroll
    for (int j = 0; j < 16; ++j) {
        const int cl = clb + j;
        const int cg = C0 + 1 + cl;
        const float up = gray[rl * PITCH + cl + 1];
        const float dn = gray[(rl + 2) * PITCH + cl + 1];
        const float lf = gray[(rl + 1) * PITCH + cl];
        const float rt = gray[(rl + 1) * PITCH + cl + 2];
        const float gy = row_ok ? __fsub_rn(dn, up) : 0.0f;
        const float gx = (cg >= 1 && cg < WW - 1) ? __fsub_rn(rt, lf) : 0.0f;

        const float mag = __fsqrt_rn(__fmaf_rn(gy, gy, __fmul_rn(gx, gx)));
        // canonicalize to theta in [0,180)
        const bool neg = gy < 0.0f;
        const float cy = fabsf(gy);
        const float cx = neg ? -gx : gx;
        // t_i ~ sin(theta - alpha_i)*mag, alpha = 30,60,90,120,150
        const float t1 = __fmaf_rn(cy, CC, -__fmul_rn(cx, SS));
        const float t2 = __fmaf_rn(cy, SS, -__fmul_rn(cx, CC));
        const float t3 = -cx;
        const float t4 = __fmaf_rn(cy, -SS, -__fmul_rn(cx, CC));
        const float t5 = __fmaf_rn(cy, -CC, -__fmul_rn(cx, SS));
        int bin = (t1 >= 0.0f) + (t2 >= 0.0f) + (t3 >= 0.0f) +
                  (t4 >= 0.0f) + (t5 >= 0.0f);
        const float s = __fmul_rn(mag, EPS);
        const float mn = fminf(fminf(fminf(fabsf(t1), fabsf(t2)),
                                     fminf(fabsf(t3), fabsf(t4))), fabsf(t5));
        const bool gz = (gy == 0.0f), xz = (gx == 0.0f);
        bool amb = (mn < s) || (cx < 0.0f && cy < s);   // incl. wrap at 180
        if (gz) { bin = 0; amb = false; }               // deterministic (r3/r5)
        else if (xz) { bin = 3; amb = false; }

        float dep = mag;
        if (__builtin_expect(amb, 0)) {
            const int qi = atomicAdd(&qcount, 1);
            if (qi < QCAP) {
                qgy[qi] = gy; qgx[qi] = gx; qmag[qi] = mag; qcell[qi] = mycell;
                dep = 0.0f;
            }
        }
        deposit(acc, bin, dep);
    }

    __syncthreads();
    // slow path: round-5 verbatim, one code copy, handled by first qcount threads
    if (tid < min(qcount, QCAP)) {
        const float gy = qgy[tid], gx = qgx[tid], mag = qmag[tid];
        const int cell = qcell[tid];
        const float a = atan2f(gy, gx);
        const int bl = bin_of(ulp_step(a, -2));
        const int bh = bin_of(ulp_step(a, +2));
        if (bl == bh) {
            atomicAdd(&hist[cell][bl], mag);
        } else {
            const int b0 = bin_of(a);
            const int bo = (b0 == bl) ? bh : bl;
            atomicAdd(&hist[cell][b0], __fmul_rn(mag, 0.65f));
            atomicAdd(&hist[cell][bo], __fmul_rn(mag, 0.35f));
        }
    }
    __syncthreads();

    // reduce across the 16 lanes of each cell (consecutive lanes)
#pragma unroll
    for (int o = 0; o < NORI; ++o) {
        float v = acc[o];
        v += __shfl_xor(v, 1);
        v += __shfl_xor(v, 2);
        v += __shfl_xor(v, 4);
        v += __shfl_xor(v, 8);
        acc[o] = v;
    }
    if ((lane & 15) == 0) {
        const int cell_r = 4 * blockIdx.y + wave;
        const int cell_c = 4 * blockIdx.x + (lane >> 4);
        float* cp = cells + (((size_t)b * NC + cell_r) * NC + cell_c) * NORI;
#pragma unroll
        for (int o = 0; o < NORI; ++o)
            cp[o] = (acc[o] + hist[mycell][o]) * (1.0f / 256.0f);
    }
}

// One thread per (b, block_row, block_col): float2 loads, L2-Hys normalize.
__global__ __launch_bounds__(256) void hog_norm_kernel(const float* __restrict__ cells,
                                                       float* __restrict__ out) {
    const int idx = blockIdx.x * 256 + threadIdx.x;
    const int total = BATCH * 31 * 31;
    if (idx >= total) return;
    const int bc = idx % 31;
    const int t = idx / 31;
    const int br = t % 31;
    const int b = t / 31;

    const float* cb = cells + (size_t)b * NC * NC * NORI;
    const float2* p0 = (const float2*)(cb + ((br) * NC + bc) * NORI);
    const float2* p1 = (const float2*)(cb + ((br + 1) * NC + bc) * NORI);
    float v[24];
#pragma unroll
    for (int q = 0; q < 6; ++q) {
        const float2 r0 = p0[q], r1 = p1[q];
        v[2 * q] = r0.x; v[2 * q + 1] = r0.y;
        v[12 + 2 * q] = r1.x; v[12 + 2 * q + 1] = r1.y;
    }
    float ss = 0.0f;
#pragma unroll
    for (int k = 0; k < 24; ++k) ss = __fadd_rn(ss, __fmul_rn(v[k], v[k]));
    const float n1 = __fsqrt_rn(__fadd_rn(ss, 1e-10f));  // EPS^2, EPS=1e-5
    float ss2 = 0.0f;
#pragma unroll
    for (int k = 0; k < 24; ++k) {
        v[k] = fminf(__fdiv_rn(v[k], n1), 0.2f);
        ss2 = __fadd_rn(ss2, __fmul_rn(v[k], v[k]));
    }
    const float n2 = __fsqrt_rn(__fadd_rn(ss2, 1e-10f));
    float* op = out + (size_t)idx * 24;
#pragma unroll
    for (int k = 0; k < 24; ++k) op[k] = __fdiv_rn(v[k], n2);
}

extern "C" void kernel_launch(void* const* d_in, const int* in_sizes, int n_in,
                              void* d_out, int out_size, void* d_ws, size_t ws_size,
                              hipStream_t stream) {
    const float* x = (const float*)d_in[0];
    float* out = (float*)d_out;
    float* cells = (float*)d_ws;  // BATCH*32*32*6 floats = 3 MB

    dim3 g1(8, 8, BATCH), b1(256);
    hog_cells_kernel<<<g1, b1, 0, stream>>>(x, cells);

    const int total = BATCH * 31 * 31;
    hog_norm_kernel<<<(total + 255) / 256, 256, 0, stream>>>(cells, out);
}

// Round 8
// 154.430 us; speedup vs baseline: 1.2166x; 1.2166x over previous
//
#include <hip/hip_runtime.h>
#include <math.h>

#define BATCH 32
#define HH 512
#define WW 512
#define NC 32        // cells per side
#define NORI 6

// ---- round-5-verbatim numpy downstream (slow path, ONE code copy) ----
__device__ __forceinline__ int bin_of(float a) {
    const float deg = __fmul_rn(a, 57.29577951308232f);
    float m = fmodf(deg, 180.0f);
    if (m < 0.0f) m = __fadd_rn(m, 180.0f);
    const int b = (int)floorf(__fdiv_rn(m, 30.0f));
    return min(max(b, 0), NORI - 1);
}
__device__ __forceinline__ float ulp_step(float x, int k) {
    const int i = __float_as_int(x);
    int key = (i >= 0) ? i : -(i & 0x7FFFFFFF);
    key += k;
    const int r = (key >= 0) ? key : (int)(0x80000000u | (unsigned)(-key));
    return __int_as_float(r);
}

struct SlowRes { float w0, w1; int b0, b1; };
__device__ __attribute__((noinline)) SlowRes slow_path(float gy, float gx, float mag) {
    const float a = atan2f(gy, gx);
    const int bl = bin_of(ulp_step(a, -2));
    const int bh = bin_of(ulp_step(a, +2));
    SlowRes r;
    if (bl == bh) {
        r.b0 = bl; r.b1 = bl; r.w0 = mag; r.w1 = 0.0f;
    } else {
        const int b0 = bin_of(a);
        r.b0 = b0; r.b1 = (b0 == bl) ? bh : bl;
        r.w0 = __fmul_rn(mag, 0.65f);
        r.w1 = __fmul_rn(mag, 0.35f);
    }
    return r;
}

__device__ __forceinline__ void deposit(float acc[NORI], int bin, float val) {
#pragma unroll
    for (int o = 0; o < NORI; ++o) acc[o] += (bin == o) ? val : 0.0f;
}

__device__ __forceinline__ float gray_at(const float* __restrict__ img, int rr, int cc) {
    const size_t idx = (size_t)rr * WW + cc;
    // (0.299*R + 0.587*G) + 0.114*B, all f32, no FMA contraction
    return __fadd_rn(__fadd_rn(__fmul_rn(0.299f, img[idx]),
                               __fmul_rn(0.587f, img[idx + (size_t)HH * WW])),
                     __fmul_rn(0.114f, img[idx + (size_t)2 * HH * WW]));
}

// Lane = one pixel column; wave = 64 cols x one 16-row cell band. Rolling
// 3-row gray window in registers (gy), __shfl for left/right neighbors (gx);
// edge lanes 0/63 fetch a halo column. No LDS, no syncthreads. Pixels within
// 1e-5 rad of a bin boundary call the noinline round-5 atan2f +-2ulp policy.
__global__ __launch_bounds__(256) void hog_cells_kernel(const float* __restrict__ x,
                                                        float* __restrict__ cells) {
    const int b = blockIdx.z;
    const int tid = threadIdx.x;
    const int wave = tid >> 6, lane = tid & 63;
    const int R0 = blockIdx.y * 64 + wave * 16;   // first computed pixel row
    const int cbase = blockIdx.x * 64;
    const int c = cbase + lane;
    const float* img = x + (size_t)b * 3 * HH * WW;

    const bool is_edge = (lane == 0) || (lane == 63);
    int hc = (lane == 0) ? (cbase - 1) : (cbase + 64);
    hc = min(max(hc, 0), WW - 1);   // clamped; value unused at image borders

    // warm-up: rows R0-1 and R0
    float gm1 = gray_at(img, max(R0 - 1, 0), c);
    float g0  = gray_at(img, R0, c);
    float hcur = 0.0f;
    if (is_edge) hcur = gray_at(img, R0, hc);

    const float CC = 0.86602540378443864676f, SS = 0.5f, EPS = 1e-5f;
    const bool col_ok = (c >= 1) && (c < WW - 1);
    float acc[NORI] = {0, 0, 0, 0, 0, 0};

    for (int r = R0; r < R0 + 16; ++r) {
        const int rn = min(r + 1, HH - 1);
        const float gp1 = gray_at(img, rn, c);
        float hnext = 0.0f;
        if (is_edge) hnext = gray_at(img, rn, hc);

        const bool row_ok = (r >= 1) && (r < HH - 1);
        const float gy = row_ok ? __fsub_rn(gp1, gm1) : 0.0f;
        float gl = __shfl(g0, (lane + 63) & 63);
        float gr = __shfl(g0, (lane + 1) & 63);
        if (lane == 0)  gl = hcur;
        if (lane == 63) gr = hcur;
        const float gx = col_ok ? __fsub_rn(gr, gl) : 0.0f;

        const float mag = __fsqrt_rn(__fmaf_rn(gy, gy, __fmul_rn(gx, gx)));
        // canonicalize to theta in [0,180)
        const bool neg = gy < 0.0f;
        const float cy = fabsf(gy);
        const float cx = neg ? -gx : gx;
        // t_i ~ sin(theta - alpha_i)*mag, alpha = 30,60,90,120,150
        const float t1 = __fmaf_rn(cy, CC, -__fmul_rn(cx, SS));
        const float t2 = __fmaf_rn(cy, SS, -__fmul_rn(cx, CC));
        const float t3 = -cx;
        const float t4 = __fmaf_rn(cy, -SS, -__fmul_rn(cx, CC));
        const float t5 = __fmaf_rn(cy, -CC, -__fmul_rn(cx, SS));
        int bin = (t1 >= 0.0f) + (t2 >= 0.0f) + (t3 >= 0.0f) +
                  (t4 >= 0.0f) + (t5 >= 0.0f);
        const float s = __fmul_rn(mag, EPS);
        const float mn = fminf(fminf(fminf(fabsf(t1), fabsf(t2)),
                                     fminf(fabsf(t3), fabsf(t4))), fabsf(t5));
        bool amb = (mn < s) || (cx < 0.0f && cy < s);   // incl. wrap at 180
        if (gy == 0.0f) { bin = 0; amb = false; }       // deterministic (r3/r5)
        else if (gx == 0.0f) { bin = 3; amb = false; }

        if (__builtin_expect(amb, 0)) {
            const SlowRes sr = slow_path(gy, gx, mag);
            deposit(acc, sr.b0, sr.w0);
            deposit(acc, sr.b1, sr.w1);
        } else {
            deposit(acc, bin, mag);
        }

        gm1 = g0; g0 = gp1; hcur = hnext;
    }

    // reduce across the 16 lanes (16 columns) of each cell
#pragma unroll
    for (int o = 0; o < NORI; ++o) {
        float v = acc[o];
        v += __shfl_xor(v, 1);
        v += __shfl_xor(v, 2);
        v += __shfl_xor(v, 4);
        v += __shfl_xor(v, 8);
        acc[o] = v;
    }
    if ((lane & 15) == 0) {
        const int cell_r = R0 >> 4;
        const int cell_c = (cbase >> 4) + (lane >> 4);
        float* cp = cells + (((size_t)b * NC + cell_r) * NC + cell_c) * NORI;
#pragma unroll
        for (int o = 0; o < NORI; ++o) cp[o] = acc[o] * (1.0f / 256.0f);
    }
}

// One thread per (b, block_row, block_col): float2 loads, L2-Hys normalize.
__global__ __launch_bounds__(256) void hog_norm_kernel(const float* __restrict__ cells,
                                                       float* __restrict__ out) {
    const int idx = blockIdx.x * 256 + threadIdx.x;
    const int total = BATCH * 31 * 31;
    if (idx >= total) return;
    const int bc = idx % 31;
    const int t = idx / 31;
    const int br = t % 31;
    const int b = t / 31;

    const float* cb = cells + (size_t)b * NC * NC * NORI;
    const float2* p0 = (const float2*)(cb + ((br) * NC + bc) * NORI);
    const float2* p1 = (const float2*)(cb + ((br + 1) * NC + bc) * NORI);
    float v[24];
#pragma unroll
    for (int q = 0; q < 6; ++q) {
        const float2 r0 = p0[q], r1 = p1[q];
        v[2 * q] = r0.x; v[2 * q + 1] = r0.y;
        v[12 + 2 * q] = r1.x; v[12 + 2 * q + 1] = r1.y;
    }
    float ss = 0.0f;
#pragma unroll
    for (int k = 0; k < 24; ++k) ss = __fadd_rn(ss, __fmul_rn(v[k], v[k]));
    const float n1 = __fsqrt_rn(__fadd_rn(ss, 1e-10f));  // EPS^2, EPS=1e-5
    float ss2 = 0.0f;
#pragma unroll
    for (int k = 0; k < 24; ++k) {
        v[k] = fminf(__fdiv_rn(v[k], n1), 0.2f);
        ss2 = __fadd_rn(ss2, __fmul_rn(v[k], v[k]));
    }
    const float n2 = __fsqrt_rn(__fadd_rn(ss2, 1e-10f));
    float* op = out + (size_t)idx * 24;
#pragma unroll
    for (int k = 0; k < 24; ++k) op[k] = __fdiv_rn(v[k], n2);
}

extern "C" void kernel_launch(void* const* d_in, const int* in_sizes, int n_in,
                              void* d_out, int out_size, void* d_ws, size_t ws_size,
                              hipStream_t stream) {
    const float* x = (const float*)d_in[0];
    float* out = (float*)d_out;
    float* cells = (float*)d_ws;  // BATCH*32*32*6 floats = 3 MB

    dim3 g1(8, 8, BATCH), b1(256);
    hog_cells_kernel<<<g1, b1, 0, stream>>>(x, cells);

    const int total = BATCH * 31 * 31;
    hog_norm_kernel<<<(total + 255) / 256, 256, 0, stream>>>(cells, out);
}

// Round 9
// 153.199 us; speedup vs baseline: 1.2264x; 1.0080x over previous
//
#include <hip/hip_runtime.h>
#include <math.h>

#define BATCH 32
#define HH 512
#define WW 512
#define NC 32        // cells per side
#define NORI 6
#define CH 262144    // HH*WW channel stride (floats)

// ---- round-5-verbatim numpy downstream (cold path, ONE inline copy) ----
__device__ __forceinline__ int bin_of(float a) {
    const float deg = __fmul_rn(a, 57.29577951308232f);
    float m = fmodf(deg, 180.0f);
    if (m < 0.0f) m = __fadd_rn(m, 180.0f);
    const int b = (int)floorf(__fdiv_rn(m, 30.0f));
    return min(max(b, 0), NORI - 1);
}
__device__ __forceinline__ float ulp_step(float x, int k) {
    const int i = __float_as_int(x);
    int key = (i >= 0) ? i : -(i & 0x7FFFFFFF);
    key += k;
    const int r = (key >= 0) ? key : (int)(0x80000000u | (unsigned)(-key));
    return __int_as_float(r);
}
__device__ __forceinline__ void deposit(float acc[NORI], int bin, float val) {
#pragma unroll
    for (int o = 0; o < NORI; ++o) acc[o] += (bin == o) ? val : 0.0f;
}
// gray with 32-bit offset: (0.299*R + 0.587*G) + 0.114*B, f32, no FMA
__device__ __forceinline__ float gray_i(const float* __restrict__ img, int off) {
    return __fadd_rn(__fadd_rn(__fmul_rn(0.299f, img[off]),
                               __fmul_rn(0.587f, img[off + CH])),
                     __fmul_rn(0.114f, img[off + 2 * CH]));
}

// Lane = one pixel column; wave = 64 cols x one 16-row cell band. Rolling
// 3-row gray window in registers (gy), __shfl for left/right neighbors (gx).
// Hot loop is call-free and rare-branch-free: ambiguous pixels (within 1e-5
// rad of a bin boundary) deposit 0 and set a row-mask bit; a post-loop cold
// phase reloads their neighbors and applies the round-5 atan2f +-2ulp policy.
__global__ __launch_bounds__(256) void hog_cells_kernel(const float* __restrict__ x,
                                                        float* __restrict__ cells) {
    const int b = blockIdx.z;
    const int tid = threadIdx.x;
    const int wave = tid >> 6, lane = tid & 63;
    const int R0 = blockIdx.y * 64 + wave * 16;   // first computed pixel row
    const int cbase = blockIdx.x * 64;
    const int c = cbase + lane;
    const float* img = x + (size_t)b * 3 * HH * WW;

    const bool is_edge = (lane == 0) || (lane == 63);
    int hc = (lane == 0) ? (cbase - 1) : (cbase + 64);
    hc = min(max(hc, 0), WW - 1);   // clamped; value unused at image borders

    // warm-up: rows R0-1 and R0
    float gm1 = gray_i(img, max(R0 - 1, 0) * WW + c);
    float g0  = gray_i(img, R0 * WW + c);
    float hcur = is_edge ? gray_i(img, R0 * WW + hc) : 0.0f;

    const float CC = 0.86602540378443864676f, SS = 0.5f, EPS = 1e-5f;
    const bool col_ok = (c >= 1) && (c < WW - 1);
    float acc[NORI] = {0, 0, 0, 0, 0, 0};
    unsigned ambmask = 0;

#pragma unroll
    for (int k = 0; k < 16; ++k) {
        const int r = R0 + k;
        const int rn = min(r + 1, HH - 1);
        const float gp1 = gray_i(img, rn * WW + c);
        const float hnext = is_edge ? gray_i(img, rn * WW + hc) : 0.0f;

        const bool row_ok = (r >= 1) && (r < HH - 1);
        const float gy = row_ok ? __fsub_rn(gp1, gm1) : 0.0f;
        float gl = __shfl(g0, (lane + 63) & 63);
        float gr = __shfl(g0, (lane + 1) & 63);
        if (lane == 0)  gl = hcur;
        if (lane == 63) gr = hcur;
        const float gx = col_ok ? __fsub_rn(gr, gl) : 0.0f;

        const float mag = __fsqrt_rn(__fmaf_rn(gy, gy, __fmul_rn(gx, gx)));
        // canonicalize to theta in [0,180)
        const bool neg = gy < 0.0f;
        const float cy = fabsf(gy);
        const float cx = neg ? -gx : gx;
        // t_i ~ sin(theta - alpha_i)*mag, alpha = 30,60,90,120,150
        const float t1 = __fmaf_rn(cy, CC, -__fmul_rn(cx, SS));
        const float t2 = __fmaf_rn(cy, SS, -__fmul_rn(cx, CC));
        const float t3 = -cx;
        const float t4 = __fmaf_rn(cy, -SS, -__fmul_rn(cx, CC));
        const float t5 = __fmaf_rn(cy, -CC, -__fmul_rn(cx, SS));
        int bin = (t1 >= 0.0f) + (t2 >= 0.0f) + (t3 >= 0.0f) +
                  (t4 >= 0.0f) + (t5 >= 0.0f);
        const float s = __fmul_rn(mag, EPS);
        const float mn = fminf(fminf(fminf(fabsf(t1), fabsf(t2)),
                                     fminf(fabsf(t3), fabsf(t4))), fabsf(t5));
        bool amb = (mn < s) || (cx < 0.0f && cy < s);   // incl. wrap at 180
        if (gy == 0.0f) { bin = 0; amb = false; }       // deterministic (r3/r5)
        else if (gx == 0.0f) { bin = 3; amb = false; }

        ambmask |= amb ? (1u << k) : 0u;
        deposit(acc, bin, amb ? 0.0f : mag);

        gm1 = g0; g0 = gp1; hcur = hnext;
    }

    // cold phase: rare (p ~ 1e-5/pixel). amb pixels are interior with
    // gy!=0 && gx!=0; recompute bitwise-identically from global memory.
    if (__any(ambmask != 0)) {
        unsigned m = ambmask;
        while (m) {
            const int k = __builtin_ctz(m);
            m &= m - 1;
            const int r = R0 + k;
            const int off = r * WW + c;
            const float gy = __fsub_rn(gray_i(img, off + WW), gray_i(img, off - WW));
            const float gx = __fsub_rn(gray_i(img, off + 1), gray_i(img, off - 1));
            const float mag = __fsqrt_rn(__fmaf_rn(gy, gy, __fmul_rn(gx, gx)));
            const float a = atan2f(gy, gx);
            const int bl = bin_of(ulp_step(a, -2));
            const int bh = bin_of(ulp_step(a, +2));
            if (bl == bh) {
                deposit(acc, bl, mag);
            } else {
                const int b0 = bin_of(a);
                const int bo = (b0 == bl) ? bh : bl;
                deposit(acc, b0, __fmul_rn(mag, 0.65f));
                deposit(acc, bo, __fmul_rn(mag, 0.35f));
            }
        }
    }

    // reduce across the 16 lanes (16 columns) of each cell
#pragma unroll
    for (int o = 0; o < NORI; ++o) {
        float v = acc[o];
        v += __shfl_xor(v, 1);
        v += __shfl_xor(v, 2);
        v += __shfl_xor(v, 4);
        v += __shfl_xor(v, 8);
        acc[o] = v;
    }
    if ((lane & 15) == 0) {
        const int cell_r = R0 >> 4;
        const int cell_c = (cbase >> 4) + (lane >> 4);
        float* cp = cells + (((size_t)b * NC + cell_r) * NC + cell_c) * NORI;
#pragma unroll
        for (int o = 0; o < NORI; ++o) cp[o] = acc[o] * (1.0f / 256.0f);
    }
}

// One thread per (b, block_row, block_col): float2 loads, L2-Hys normalize.
__global__ __launch_bounds__(256) void hog_norm_kernel(const float* __restrict__ cells,
                                                       float* __restrict__ out) {
    const int idx = blockIdx.x * 256 + threadIdx.x;
    const int total = BATCH * 31 * 31;
    if (idx >= total) return;
    const int bc = idx % 31;
    const int t = idx / 31;
    const int br = t % 31;
    const int b = t / 31;

    const float* cb = cells + (size_t)b * NC * NC * NORI;
    const float2* p0 = (const float2*)(cb + ((br) * NC + bc) * NORI);
    const float2* p1 = (const float2*)(cb + ((br + 1) * NC + bc) * NORI);
    float v[24];
#pragma unroll
    for (int q = 0; q < 6; ++q) {
        const float2 r0 = p0[q], r1 = p1[q];
        v[2 * q] = r0.x; v[2 * q + 1] = r0.y;
        v[12 + 2 * q] = r1.x; v[12 + 2 * q + 1] = r1.y;
    }
    float ss = 0.0f;
#pragma unroll
    for (int k = 0; k < 24; ++k) ss = __fadd_rn(ss, __fmul_rn(v[k], v[k]));
    const float n1 = __fsqrt_rn(__fadd_rn(ss, 1e-10f));  // EPS^2, EPS=1e-5
    float ss2 = 0.0f;
#pragma unroll
    for (int k = 0; k < 24; ++k) {
        v[k] = fminf(__fdiv_rn(v[k], n1), 0.2f);
        ss2 = __fadd_rn(ss2, __fmul_rn(v[k], v[k]));
    }
    const float n2 = __fsqrt_rn(__fadd_rn(ss2, 1e-10f));
    float* op = out + (size_t)idx * 24;
#pragma unroll
    for (int k = 0; k < 24; ++k) op[k] = __fdiv_rn(v[k], n2);
}

extern "C" void kernel_launch(void* const* d_in, const int* in_sizes, int n_in,
                              void* d_out, int out_size, void* d_ws, size_t ws_size,
                              hipStream_t stream) {
    const float* x = (const float*)d_in[0];
    float* out = (float*)d_out;
    float* cells = (float*)d_ws;  // BATCH*32*32*6 floats = 3 MB

    dim3 g1(8, 8, BATCH), b1(256);
    hog_cells_kernel<<<g1, b1, 0, stream>>>(x, cells);

    const int total = BATCH * 31 * 31;
    hog_norm_kernel<<<(total + 255) / 256, 256, 0, stream>>>(cells, out);
}

// Round 10
// 152.759 us; speedup vs baseline: 1.2299x; 1.0029x over previous
//
#include <hip/hip_runtime.h>
#include <math.h>

#define BATCH 32
#define HH 512
#define WW 512
#define NC 32        // cells per side
#define NORI 6
#define CH 262144    // HH*WW channel stride (floats)

// ---- round-5-verbatim numpy downstream (cold path, ONE inline copy) ----
__device__ __forceinline__ int bin_of(float a) {
    const float deg = __fmul_rn(a, 57.29577951308232f);
    float m = fmodf(deg, 180.0f);
    if (m < 0.0f) m = __fadd_rn(m, 180.0f);
    const int b = (int)floorf(__fdiv_rn(m, 30.0f));
    return min(max(b, 0), NORI - 1);
}
__device__ __forceinline__ float ulp_step(float x, int k) {
    const int i = __float_as_int(x);
    int key = (i >= 0) ? i : -(i & 0x7FFFFFFF);
    key += k;
    const int r = (key >= 0) ? key : (int)(0x80000000u | (unsigned)(-key));
    return __int_as_float(r);
}
__device__ __forceinline__ void deposit(float acc[NORI], int bin, float val) {
#pragma unroll
    for (int o = 0; o < NORI; ++o) acc[o] += (bin == o) ? val : 0.0f;
}
// (0.299*R + 0.587*G) + 0.114*B, f32, no FMA contraction
__device__ __forceinline__ float gray_comb(float r, float g, float b) {
    return __fadd_rn(__fadd_rn(__fmul_rn(0.299f, r), __fmul_rn(0.587f, g)),
                     __fmul_rn(0.114f, b));
}
__device__ __forceinline__ float gray_i(const float* __restrict__ img, int off) {
    return gray_comb(img[off], img[off + CH], img[off + 2 * CH]);
}
__device__ __forceinline__ float4 gray4(const float* __restrict__ img, int off) {
    const float4 r = *(const float4*)(img + off);
    const float4 g = *(const float4*)(img + off + CH);
    const float4 b = *(const float4*)(img + off + 2 * CH);
    float4 o;
    o.x = gray_comb(r.x, g.x, b.x);
    o.y = gray_comb(r.y, g.y, b.y);
    o.z = gray_comb(r.z, g.z, b.z);
    o.w = gray_comb(r.w, g.w, b.w);
    return o;
}

__device__ __forceinline__ void hot_pixel(float gy, float gx, int bitk,
                                          float acc[NORI], unsigned& ambmask) {
    const float mag = __fsqrt_rn(__fmaf_rn(gy, gy, __fmul_rn(gx, gx)));
    // canonicalize to theta in [0,180)
    const bool neg = gy < 0.0f;
    const float cy = fabsf(gy);
    const float cx = neg ? -gx : gx;
    // t_i ~ sin(theta - alpha_i), alpha = 30,60,90,120,150 (shared products)
    const float pa = __fmul_rn(cy, 0.86602540378443864676f);
    const float pb = __fmul_rn(cx, 0.5f);
    const float pc = __fmul_rn(cy, 0.5f);
    const float pd = __fmul_rn(cx, 0.86602540378443864676f);
    const float t1 = __fsub_rn(pa, pb);
    const float t2 = __fsub_rn(pc, pd);
    const float t3 = -cx;
    const float t4 = -__fadd_rn(pc, pd);
    const float t5 = -__fadd_rn(pa, pb);
    int bin = (t1 >= 0.0f) + (t2 >= 0.0f) + (t3 >= 0.0f) +
              (t4 >= 0.0f) + (t5 >= 0.0f);
    const float s = __fmul_rn(mag, 1e-5f);
    const float mn = fminf(fminf(fminf(fabsf(t1), fabsf(t2)),
                                 fminf(fabsf(t3), fabsf(t4))), fabsf(t5));
    bool amb = (mn < s) || (cx < 0.0f && cy < s);   // incl. wrap at 180
    if (gy == 0.0f) { bin = 0; amb = false; }       // deterministic (r3/r5)
    else if (gx == 0.0f) { bin = 3; amb = false; }
    ambmask |= amb ? (1u << bitk) : 0u;
    deposit(acc, bin, amb ? 0.0f : mag);
}

// Lane = 4 adjacent columns (float4 channel loads); wave = 256 cols x 4 rows;
// block = 4 waves = one 16-row cell-row x 256 cols (16 cells). Rolling 3-row
// float4 gray window; interior gx needs no shfl, quad edges use 2 shfls/row.
// Ambiguous pixels (within 1e-5 rad of a bin boundary) set a mask bit and are
// re-done post-loop with the round-5 atan2f +-2ulp policy from global memory.
__global__ __launch_bounds__(256) void hog_cells_kernel(const float* __restrict__ x,
                                                        float* __restrict__ cells) {
    const int b = blockIdx.z;
    const int tid = threadIdx.x;
    const int wave = tid >> 6, lane = tid & 63;
    const int by = blockIdx.y;              // cell row
    const int R0 = by * 16 + wave * 4;      // this wave's first pixel row
    const int C0 = blockIdx.x * 256;
    const int c0 = C0 + lane * 4;
    const float* img = x + (size_t)b * 3 * HH * WW;

    __shared__ float hist[16][NORI];
    if (tid < 16 * NORI) ((float*)hist)[tid] = 0.0f;
    __syncthreads();

    // single halo column per wave: left block needs abs col 256 (lane 63),
    // right block needs abs col 255 (lane 0). Image borders give gx=0 instead.
    const bool left_blk = (blockIdx.x == 0);
    const int hc = left_blk ? 256 : 255;
    const bool is_h = (lane == (left_blk ? 63 : 0));

    float4 gm1 = gray4(img, max(R0 - 1, 0) * WW + c0);
    float4 g0  = gray4(img, R0 * WW + c0);
    float hcur = is_h ? gray_i(img, R0 * WW + hc) : 0.0f;

    float acc[NORI] = {0, 0, 0, 0, 0, 0};
    unsigned ambmask = 0;

#pragma unroll
    for (int k = 0; k < 4; ++k) {
        const int r = R0 + k;
        const int rn = min(r + 1, HH - 1);
        const float4 gp1 = gray4(img, rn * WW + c0);
        const float hnext = is_h ? gray_i(img, rn * WW + hc) : 0.0f;

        const bool row_ok = (r >= 1) && (r < HH - 1);
        const float gy0 = row_ok ? __fsub_rn(gp1.x, gm1.x) : 0.0f;
        const float gy1 = row_ok ? __fsub_rn(gp1.y, gm1.y) : 0.0f;
        const float gy2 = row_ok ? __fsub_rn(gp1.z, gm1.z) : 0.0f;
        const float gy3 = row_ok ? __fsub_rn(gp1.w, gm1.w) : 0.0f;

        float left  = __shfl(g0.w, (lane + 63) & 63);
        float right = __shfl(g0.x, (lane + 1) & 63);
        if (is_h) { if (left_blk) right = hcur; else left = hcur; }

        float gx0 = __fsub_rn(g0.y, left);
        const float gx1 = __fsub_rn(g0.z, g0.x);
        const float gx2 = __fsub_rn(g0.w, g0.y);
        float gx3 = __fsub_rn(right, g0.z);
        if (c0 == 0) gx0 = 0.0f;             // image left border
        if (c0 + 3 == WW - 1) gx3 = 0.0f;    // image right border

        hot_pixel(gy0, gx0, 4 * k + 0, acc, ambmask);
        hot_pixel(gy1, gx1, 4 * k + 1, acc, ambmask);
        hot_pixel(gy2, gx2, 4 * k + 2, acc, ambmask);
        hot_pixel(gy3, gx3, 4 * k + 3, acc, ambmask);

        gm1 = g0; g0 = gp1; hcur = hnext;
    }

    // cold phase: rare. amb pixels are interior with gy!=0 && gx!=0;
    // recompute bitwise-identically from global memory.
    if (__any(ambmask != 0)) {
        unsigned m = ambmask;
        while (m) {
            const int bit = __builtin_ctz(m);
            m &= m - 1;
            const int r = R0 + (bit >> 2);
            const int c = c0 + (bit & 3);
            const int off = r * WW + c;
            const float gy = __fsub_rn(gray_i(img, off + WW), gray_i(img, off - WW));
            const float gx = __fsub_rn(gray_i(img, off + 1), gray_i(img, off - 1));
            const float mag = __fsqrt_rn(__fmaf_rn(gy, gy, __fmul_rn(gx, gx)));
            const float a = atan2f(gy, gx);
            const int bl = bin_of(ulp_step(a, -2));
            const int bh = bin_of(ulp_step(a, +2));
            if (bl == bh) {
                deposit(acc, bl, mag);
            } else {
                const int b0 = bin_of(a);
                const int bo = (b0 == bl) ? bh : bl;
                deposit(acc, b0, __fmul_rn(mag, 0.65f));
                deposit(acc, bo, __fmul_rn(mag, 0.35f));
            }
        }
    }

    // reduce the 4 lanes of each cell (16 cols = lanes 4c..4c+3)
#pragma unroll
    for (int o = 0; o < NORI; ++o) {
        float v = acc[o];
        v += __shfl_xor(v, 1);
        v += __shfl_xor(v, 2);
        acc[o] = v;
    }
    if ((lane & 3) == 0) {
        const int cell = lane >> 2;
#pragma unroll
        for (int o = 0; o < NORI; ++o) atomicAdd(&hist[cell][o], acc[o]);
    }
    __syncthreads();
    if (tid < 96) {
        const int cell = tid / 6, o = tid - cell * 6;
        cells[(((size_t)b * NC + by) * NC + ((C0 >> 4) + cell)) * NORI + o] =
            hist[cell][o] * (1.0f / 256.0f);
    }
}

// One thread per (b, block_row, block_col): float2 loads, L2-Hys normalize.
__global__ __launch_bounds__(256) void hog_norm_kernel(const float* __restrict__ cells,
                                                       float* __restrict__ out) {
    const int idx = blockIdx.x * 256 + threadIdx.x;
    const int total = BATCH * 31 * 31;
    if (idx >= total) return;
    const int bc = idx % 31;
    const int t = idx / 31;
    const int br = t % 31;
    const int b = t / 31;

    const float* cb = cells + (size_t)b * NC * NC * NORI;
    const float2* p0 = (const float2*)(cb + ((br) * NC + bc) * NORI);
    const float2* p1 = (const float2*)(cb + ((br + 1) * NC + bc) * NORI);
    float v[24];
#pragma unroll
    for (int q = 0; q < 6; ++q) {
        const float2 r0 = p0[q], r1 = p1[q];
        v[2 * q] = r0.x; v[2 * q + 1] = r0.y;
        v[12 + 2 * q] = r1.x; v[12 + 2 * q + 1] = r1.y;
    }
    float ss = 0.0f;
#pragma unroll
    for (int k = 0; k < 24; ++k) ss = __fadd_rn(ss, __fmul_rn(v[k], v[k]));
    const float n1 = __fsqrt_rn(__fadd_rn(ss, 1e-10f));  // EPS^2, EPS=1e-5
    float ss2 = 0.0f;
#pragma unroll
    for (int k = 0; k < 24; ++k) {
        v[k] = fminf(__fdiv_rn(v[k], n1), 0.2f);
        ss2 = __fadd_rn(ss2, __fmul_rn(v[k], v[k]));
    }
    const float n2 = __fsqrt_rn(__fadd_rn(ss2, 1e-10f));
    float* op = out + (size_t)idx * 24;
#pragma unroll
    for (int k = 0; k < 24; ++k) op[k] = __fdiv_rn(v[k], n2);
}

extern "C" void kernel_launch(void* const* d_in, const int* in_sizes, int n_in,
                              void* d_out, int out_size, void* d_ws, size_t ws_size,
                              hipStream_t stream) {
    const float* x = (const float*)d_in[0];
    float* out = (float*)d_out;
    float* cells = (float*)d_ws;  // BATCH*32*32*6 floats = 3 MB

    dim3 g1(2, NC, BATCH), b1(256);
    hog_cells_kernel<<<g1, b1, 0, stream>>>(x, cells);

    const int total = BATCH * 31 * 31;
    hog_norm_kernel<<<(total + 255) / 256, 256, 0, stream>>>(cells, out);
}